// Round 1
// baseline (333.811 us; speedup 1.0000x reference)
//
#include <hip/hip_runtime.h>

// Problem constants
#define NB 16
#define NC 64
#define HW 160
#define NOUT 64
#define KEXP 4
#define NHID 17
#define COLS 162   // 160 + 2 halo cols
#define CPAD 40    // 32 channels padded to 40 shorts -> 80B col stride, conflict-free b128

typedef __attribute__((ext_vector_type(8))) short short8;
typedef __attribute__((ext_vector_type(4))) float f32x4;

static __device__ __forceinline__ unsigned short f2bf(float f) {
  unsigned int u = __builtin_bit_cast(unsigned int, f);
  u += 0x7fffu + ((u >> 16) & 1u);
  return (unsigned short)(u >> 16);
}

// ---------------- Kernel 1: global average pool ----------------
__global__ __launch_bounds__(256) void pool_kernel(const float* __restrict__ x,
                                                   float* __restrict__ pooled) {
  int bc = blockIdx.x;  // 0..1023  (b*64+c)
  const float4* p = (const float4*)(x + (size_t)bc * 25600);
  float s = 0.f;
  for (int i = threadIdx.x; i < 6400; i += 256) {
    float4 v = p[i];
    s += v.x + v.y + v.z + v.w;
  }
#pragma unroll
  for (int off = 32; off > 0; off >>= 1) s += __shfl_down(s, off);
  __shared__ float red[4];
  if ((threadIdx.x & 63) == 0) red[threadIdx.x >> 6] = s;
  __syncthreads();
  if (threadIdx.x == 0)
    pooled[bc] = (red[0] + red[1] + red[2] + red[3]) * (1.0f / 25600.0f);
}

// ---------------- Kernel 2: attention + weight aggregation ----------------
// packed layout (short8 units): flat = b*4608 + ((mb*2+q)*9+t)*64 + lane
//   value[e] = bf16( sum_k attn[b][k] * weight[k][o][c][i][j] )
//   o = mb*16 + (lane&15), c = q*32 + (lane>>4)*8 + e, i=t/3, j=t%3
__global__ __launch_bounds__(256) void attn_agg_kernel(
    const float* __restrict__ pooled, const float* __restrict__ fc1,
    const float* __restrict__ fc2, const float* __restrict__ wgt,
    const float* __restrict__ biasp, float* __restrict__ aggb,
    short* __restrict__ packed) {
  int b = blockIdx.x;  // 0..15
  // redundant per-thread attention compute (tiny)
  float attn[KEXP];
  {
    float hid[NHID];
#pragma unroll
    for (int j = 0; j < NHID; ++j) {
      float s = 0.f;
      for (int c = 0; c < NC; ++c) s += pooled[b * NC + c] * fc1[j * NC + c];
      hid[j] = fmaxf(s, 0.f);
    }
    float lg[KEXP];
    float m = -1e30f;
#pragma unroll
    for (int k = 0; k < KEXP; ++k) {
      float s = 0.f;
      for (int j = 0; j < NHID; ++j) s += hid[j] * fc2[k * NHID + j];
      s *= (1.0f / 34.0f);
      lg[k] = s;
      m = fmaxf(m, s);
    }
    float den = 0.f;
#pragma unroll
    for (int k = 0; k < KEXP; ++k) {
      lg[k] = expf(lg[k] - m);
      den += lg[k];
    }
#pragma unroll
    for (int k = 0; k < KEXP; ++k) attn[k] = lg[k] / den;
  }
  int tid = threadIdx.x;
  if (tid < NOUT) {
    float s = 0.f;
#pragma unroll
    for (int k = 0; k < KEXP; ++k) s += attn[k] * biasp[k * NOUT + tid];
    aggb[b * NOUT + tid] = s;
  }
  // pack aggregated weights in MFMA A-fragment order
  for (int p = tid; p < 4608; p += 256) {
    int l = p & 63;
    int t = (p >> 6) % 9;
    int q = (p / 576) & 1;
    int mb = p / 1152;
    int o = mb * 16 + (l & 15);
    int cbase = q * 32 + (l >> 4) * 8;
    int i = t / 3, jj = t % 3;
    unsigned short vals[8];
#pragma unroll
    for (int e = 0; e < 8; ++e) {
      int c = cbase + e;
      float s = 0.f;
#pragma unroll
      for (int k = 0; k < KEXP; ++k)
        s += attn[k] * wgt[(((k * NOUT + o) * NC + c) * 9) + i * 3 + jj];
      vals[e] = f2bf(s);
    }
    short8 v;
#pragma unroll
    for (int e = 0; e < 8; ++e) v[e] = (short)vals[e];
    ((short8*)packed)[b * 4608 + p] = v;
  }
}

// ---------------- Kernel 3: implicit-GEMM conv via MFMA ----------------
// block = (b, 2-row strip). 8 waves: wm = wid&3 (16 out-ch), wr = wid>>2 (row).
// Each wave: 10 frags of 16x16 (out-ch x col), K = 2 halves x 9 taps x 32 ch.
__global__ __launch_bounds__(512, 4) void conv_kernel(
    const float* __restrict__ x, const short* __restrict__ packed,
    const float* __restrict__ aggb, float* __restrict__ out) {
  __shared__ short xs[4 * COLS * CPAD];  // 51840 B

  int bx = blockIdx.x;
  int sw = (bx & 7) * 160 + (bx >> 3);  // XCD-contiguous swizzle (1280 = 8*160)
  int b = sw / 80;
  int strip = sw % 80;
  int h0 = strip * 2;

  int tid = threadIdx.x;
  int lane = tid & 63;
  int wid = tid >> 6;
  int wm = wid & 3;
  int wr = wid >> 2;
  int l15 = lane & 15;
  int lg = lane >> 4;

  f32x4 acc[10];
#pragma unroll
  for (int i = 0; i < 10; ++i) acc[i] = (f32x4)(0.f);

  const float* xb = x + (size_t)b * NC * 25600;

  for (int q = 0; q < 2; ++q) {
    // ---- stage half q: x[b][q*32..q*32+31][h0-1..h0+2][:] -> bf16 LDS ----
    for (int jjob = tid; jjob < 4 * 8 * COLS; jjob += 512) {
      int xcol = jjob % COLS;      // 0..161  (input col = xcol-1)
      int rc = jjob / COLS;        // 0..31
      int r = rc >> 3;             // 0..3
      int cg = rc & 7;             // 4-channel group
      int row = h0 - 1 + r;
      int w = xcol - 1;
      int cl = cg * 4;
      float v0 = 0.f, v1 = 0.f, v2 = 0.f, v3 = 0.f;
      if ((unsigned)row < 160u && (unsigned)w < 160u) {
        const float* p = xb + ((size_t)(q * 32 + cl) * 160 + row) * 160 + w;
        v0 = p[0];
        v1 = p[25600];
        v2 = p[51200];
        v3 = p[76800];
      }
      unsigned long long pk =
          (unsigned long long)f2bf(v0) | ((unsigned long long)f2bf(v1) << 16) |
          ((unsigned long long)f2bf(v2) << 32) | ((unsigned long long)f2bf(v3) << 48);
      *(unsigned long long*)(&xs[(r * COLS + xcol) * CPAD + cl]) = pk;
    }
    __syncthreads();

    const short8* apq =
        (const short8*)packed + (((b * 4 + wm) * 2 + q) * 9) * 64 + lane;
#pragma unroll
    for (int t = 0; t < 9; ++t) {
      short8 a = apq[t * 64];  // coalesced 16B/lane, L2-resident
      int ti = t / 3, tj = t % 3;
      const short* bsrc = &xs[((wr + ti) * COLS + tj + l15) * CPAD + lg * 8];
#pragma unroll
      for (int nf = 0; nf < 10; ++nf) {
        short8 bfrag = *(const short8*)(bsrc + nf * 16 * CPAD);
        acc[nf] = __builtin_amdgcn_mfma_f32_16x16x32_bf16(a, bfrag, acc[nf], 0, 0, 0);
      }
    }
    __syncthreads();
  }

  // ---- epilogue: add bias, store ----
  int h = h0 + wr;
  int obase = wm * 16 + lg * 4;
  float bv[4];
#pragma unroll
  for (int rr = 0; rr < 4; ++rr) bv[rr] = aggb[b * NOUT + obase + rr];
#pragma unroll
  for (int nf = 0; nf < 10; ++nf) {
    int wcol = nf * 16 + l15;
#pragma unroll
    for (int rr = 0; rr < 4; ++rr) {
      out[(((size_t)(b * NOUT + obase + rr)) * 160 + h) * 160 + wcol] =
          acc[nf][rr] + bv[rr];
    }
  }
}

extern "C" void kernel_launch(void* const* d_in, const int* in_sizes, int n_in,
                              void* d_out, int out_size, void* d_ws, size_t ws_size,
                              hipStream_t stream) {
  const float* x = (const float*)d_in[0];
  const float* fc1 = (const float*)d_in[1];
  const float* fc2 = (const float*)d_in[2];
  const float* wgt = (const float*)d_in[3];
  const float* biasp = (const float*)d_in[4];
  float* out = (float*)d_out;

  // ws layout: pooled [1024 f32] | aggb [1024 f32] | packed [16*4608 short8]
  float* pooled = (float*)d_ws;
  float* aggb = pooled + 1024;
  short* packed = (short*)((char*)d_ws + 8192);

  pool_kernel<<<NB * NC, 256, 0, stream>>>(x, pooled);
  attn_agg_kernel<<<NB, 256, 0, stream>>>(pooled, fc1, fc2, wgt, biasp, aggb, packed);
  conv_kernel<<<NB * 80, 512, 0, stream>>>(x, packed, aggb, out);
}

// Round 2
// 250.402 us; speedup vs baseline: 1.3331x; 1.3331x over previous
//
#include <hip/hip_runtime.h>

// Problem constants
#define NB 16
#define NC 64
#define HW 160
#define NOUT 64
#define KEXP 4
#define NHID 17
#define COLS 162   // 160 + 2 halo cols
#define CPAD 40    // 32 channels padded to 40 shorts -> 80B col stride, conflict-free b128

typedef __attribute__((ext_vector_type(8))) short short8;
typedef __attribute__((ext_vector_type(4))) float f32x4;

static __device__ __forceinline__ unsigned short f2bf(float f) {
  unsigned int u = __builtin_bit_cast(unsigned int, f);
  u += 0x7fffu + ((u >> 16) & 1u);
  return (unsigned short)(u >> 16);
}

// ---------------- Kernel 1: global average pool ----------------
__global__ __launch_bounds__(256) void pool_kernel(const float* __restrict__ x,
                                                   float* __restrict__ pooled) {
  int bc = blockIdx.x;  // 0..1023  (b*64+c)
  const float4* p = (const float4*)(x + (size_t)bc * 25600);
  float s = 0.f;
  for (int i = threadIdx.x; i < 6400; i += 256) {
    float4 v = p[i];
    s += v.x + v.y + v.z + v.w;
  }
#pragma unroll
  for (int off = 32; off > 0; off >>= 1) s += __shfl_down(s, off);
  __shared__ float red[4];
  if ((threadIdx.x & 63) == 0) red[threadIdx.x >> 6] = s;
  __syncthreads();
  if (threadIdx.x == 0)
    pooled[bc] = (red[0] + red[1] + red[2] + red[3]) * (1.0f / 25600.0f);
}

// ---------------- Kernel 2a: attention (tiny) ----------------
// grid 16 blocks x 64 threads. Wave-parallel fc1 reduction; writes
// attn[b][4] and aggb[b][64].
__global__ __launch_bounds__(64) void attn_kernel(
    const float* __restrict__ pooled, const float* __restrict__ fc1,
    const float* __restrict__ fc2, const float* __restrict__ biasp,
    float* __restrict__ attn_ws, float* __restrict__ aggb) {
  int b = blockIdx.x;
  int lane = threadIdx.x;  // 0..63
  float pc = pooled[b * NC + lane];
  float hid[NHID];
#pragma unroll
  for (int j = 0; j < NHID; ++j) {
    float partial = pc * fc1[j * NC + lane];  // coalesced
#pragma unroll
    for (int off = 32; off > 0; off >>= 1) partial += __shfl_xor(partial, off);
    hid[j] = fmaxf(partial, 0.f);
  }
  float lg[KEXP];
  float m = -1e30f;
#pragma unroll
  for (int k = 0; k < KEXP; ++k) {
    float s = 0.f;
#pragma unroll
    for (int j = 0; j < NHID; ++j) s += hid[j] * fc2[k * NHID + j];
    s *= (1.0f / 34.0f);
    lg[k] = s;
    m = fmaxf(m, s);
  }
  float den = 0.f;
#pragma unroll
  for (int k = 0; k < KEXP; ++k) {
    lg[k] = __expf(lg[k] - m);
    den += lg[k];
  }
  float inv = 1.0f / den;
  float at[KEXP];
#pragma unroll
  for (int k = 0; k < KEXP; ++k) at[k] = lg[k] * inv;
  if (lane < KEXP) attn_ws[b * KEXP + lane] = at[lane];
  float s = 0.f;
#pragma unroll
  for (int k = 0; k < KEXP; ++k) s += at[k] * biasp[k * NOUT + lane];
  aggb[b * NOUT + lane] = s;
}

// ---------------- Kernel 2b: weight aggregation + pack ----------------
// packed layout (short8 units): flat = b*4608 + ((mb*2+q)*9+t)*64 + lane
//   value[e] = bf16( sum_k attn[b][k] * weight[k][o][c][i][j] )
//   o = mb*16 + (lane&15), c = q*32 + (lane>>4)*8 + e, i=t/3, j=t%3
// grid = 16*18 blocks x 256 threads, exactly one packed element per thread.
__global__ __launch_bounds__(256) void pack_kernel(
    const float* __restrict__ attn_ws, const float* __restrict__ wgt,
    short* __restrict__ packed) {
  int b = blockIdx.x / 18;
  int p = (blockIdx.x % 18) * 256 + threadIdx.x;  // 0..4607
  float a[KEXP];
#pragma unroll
  for (int k = 0; k < KEXP; ++k) a[k] = attn_ws[b * KEXP + k];
  int l = p & 63;
  int t = (p >> 6) % 9;
  int q = (p / 576) & 1;
  int mb = p / 1152;
  int o = mb * 16 + (l & 15);
  int cbase = q * 32 + (l >> 4) * 8;
  int i = t / 3, jj = t % 3;
  const float* wbase = wgt + (size_t)o * NC * 9 + i * 3 + jj;
  short8 v;
#pragma unroll
  for (int e = 0; e < 8; ++e) {
    int c = cbase + e;
    float s = 0.f;
#pragma unroll
    for (int k = 0; k < KEXP; ++k)
      s += a[k] * wbase[(size_t)k * NOUT * NC * 9 + (size_t)c * 9];
    v[e] = (short)f2bf(s);
  }
  ((short8*)packed)[b * 4608 + p] = v;
}

// ---------------- Kernel 3: implicit-GEMM conv via MFMA ----------------
// block = (b, 2-row strip). 8 waves: wm = wid&3 (16 out-ch), wr = wid>>2 (row).
// Each wave: 10 frags of 16x16 (out-ch x col), K = 2 halves x 9 taps x 32 ch.
__global__ __launch_bounds__(512, 4) void conv_kernel(
    const float* __restrict__ x, const short* __restrict__ packed,
    const float* __restrict__ aggb, float* __restrict__ out) {
  __shared__ short xs[4 * COLS * CPAD];  // 51840 B

  int bx = blockIdx.x;
  int sw = (bx & 7) * 160 + (bx >> 3);  // XCD-contiguous swizzle (1280 = 8*160)
  int b = sw / 80;
  int strip = sw % 80;
  int h0 = strip * 2;

  int tid = threadIdx.x;
  int lane = tid & 63;
  int wid = tid >> 6;
  int wm = wid & 3;
  int wr = wid >> 2;
  int l15 = lane & 15;
  int lg = lane >> 4;

  f32x4 acc[10];
#pragma unroll
  for (int i = 0; i < 10; ++i) acc[i] = (f32x4)(0.f);

  const float* xb = x + (size_t)b * NC * 25600;

  for (int q = 0; q < 2; ++q) {
    // ---- stage half q: x[b][q*32..q*32+31][h0-1..h0+2][:] -> bf16 LDS ----
    for (int jjob = tid; jjob < 4 * 8 * COLS; jjob += 512) {
      int xcol = jjob % COLS;      // 0..161  (input col = xcol-1)
      int rc = jjob / COLS;        // 0..31
      int r = rc >> 3;             // 0..3
      int cg = rc & 7;             // 4-channel group
      int row = h0 - 1 + r;
      int w = xcol - 1;
      int cl = cg * 4;
      float v0 = 0.f, v1 = 0.f, v2 = 0.f, v3 = 0.f;
      if ((unsigned)row < 160u && (unsigned)w < 160u) {
        const float* p = xb + ((size_t)(q * 32 + cl) * 160 + row) * 160 + w;
        v0 = p[0];
        v1 = p[25600];
        v2 = p[51200];
        v3 = p[76800];
      }
      unsigned long long pk =
          (unsigned long long)f2bf(v0) | ((unsigned long long)f2bf(v1) << 16) |
          ((unsigned long long)f2bf(v2) << 32) | ((unsigned long long)f2bf(v3) << 48);
      *(unsigned long long*)(&xs[(r * COLS + xcol) * CPAD + cl]) = pk;
    }
    __syncthreads();

    const short8* apq =
        (const short8*)packed + (((b * 4 + wm) * 2 + q) * 9) * 64 + lane;
#pragma unroll
    for (int t = 0; t < 9; ++t) {
      short8 a = apq[t * 64];  // coalesced 16B/lane, L2-resident
      int ti = t / 3, tj = t % 3;
      const short* bsrc = &xs[((wr + ti) * COLS + tj + l15) * CPAD + lg * 8];
#pragma unroll
      for (int nf = 0; nf < 10; ++nf) {
        short8 bfrag = *(const short8*)(bsrc + nf * 16 * CPAD);
        acc[nf] = __builtin_amdgcn_mfma_f32_16x16x32_bf16(a, bfrag, acc[nf], 0, 0, 0);
      }
    }
    __syncthreads();
  }

  // ---- epilogue: add bias, store ----
  int h = h0 + wr;
  int obase = wm * 16 + lg * 4;
  float bv[4];
#pragma unroll
  for (int rr = 0; rr < 4; ++rr) bv[rr] = aggb[b * NOUT + obase + rr];
#pragma unroll
  for (int nf = 0; nf < 10; ++nf) {
    int wcol = nf * 16 + l15;
#pragma unroll
    for (int rr = 0; rr < 4; ++rr) {
      out[(((size_t)(b * NOUT + obase + rr)) * 160 + h) * 160 + wcol] =
          acc[nf][rr] + bv[rr];
    }
  }
}

extern "C" void kernel_launch(void* const* d_in, const int* in_sizes, int n_in,
                              void* d_out, int out_size, void* d_ws, size_t ws_size,
                              hipStream_t stream) {
  const float* x = (const float*)d_in[0];
  const float* fc1 = (const float*)d_in[1];
  const float* fc2 = (const float*)d_in[2];
  const float* wgt = (const float*)d_in[3];
  const float* biasp = (const float*)d_in[4];
  float* out = (float*)d_out;

  // ws layout: pooled [1024 f32] | aggb [1024 f32] | attn [64 f32] | packed
  float* pooled = (float*)d_ws;
  float* aggb = pooled + 1024;
  float* attn_ws = aggb + 1024;
  short* packed = (short*)((char*)d_ws + 12288);

  pool_kernel<<<NB * NC, 256, 0, stream>>>(x, pooled);
  attn_kernel<<<NB, 64, 0, stream>>>(pooled, fc1, fc2, biasp, attn_ws, aggb);
  pack_kernel<<<NB * 18, 256, 0, stream>>>(attn_ws, wgt, packed);
  conv_kernel<<<NB * 80, 512, 0, stream>>>(x, packed, aggb, out);
}